// Round 5
// baseline (89.543 us; speedup 1.0000x reference)
//
#include <hip/hip_runtime.h>

#define D 16
#define OUTD 153                 // 1 + 16 + 16 + 120
#define THREADS 256
#define GPW 2                    // row-groups (of 4 rows) per wave, fully unrolled

// Barrier-free, LDS-free design:
//  - each wave loads 4 rows as ONE coalesced 256B dword load (lane L -> x_flat[g*64+L])
//  - output element c = k*64 + lane (k=0..2) needs x_i*x_j: gathered via 2 shfl
//    (ds_bpermute register crossbar); (i, j, scale, mode) depend only on lane ->
//    computed ONCE per wave as per-lane constants
//  - stores: global_store_dword at consecutive lane addresses -> 256B coalesced
//  - no __syncthreads anywhere: 32 independent waves/CU keep the store pipe at
//    full duty cycle (the R2/R4 barrier drain forced ~25% idle)

__global__ __launch_bounds__(THREADS) void taylor_fm_kernel(const float* __restrict__ x,
                                                            float* __restrict__ out,
                                                            int nrows) {
    const int tid  = threadIdx.x;
    const int lane = tid & 63;
    const int wid  = tid >> 6;
    const int ngroups = nrows >> 2;                       // 4 rows per group
    const long long g0 = ((long long)blockIdx.x * 4 + wid) * GPW;

    // ---- per-lane constants for the 3 rounds (c = k*64 + lane) ----
    int   ii[3], jj[3];
    float sc[3];
    bool  quad[3];
#pragma unroll
    for (int k = 0; k < 3; ++k) {
        const int c = k * 64 + lane;
        int i = 0, j = 0; float s = 0.f; bool q = true;
        if (c == 0)        { s = 0.f; }                                    // -> overridden to 1.0
        else if (c < 17)   { i = c - 1;  s = 0.5f; q = false; }            // x / 16^0.25
        else if (c < 33)   { i = c - 17; j = i; s = 0.17677669529663687f; }// x^2/(4*sqrt2)
        else if (c < OUTD) { int t = c - 33; i = 0;                        // x_i*x_j / 4
                             while (t >= 15 - i) { t -= 15 - i; ++i; }
                             j = i + 1 + t; s = 0.25f; }
        ii[k] = i; jj[k] = j; sc[k] = s; quad[k] = q;
    }

    // ---- issue all group loads upfront (1 dword/lane per group) ----
    float xv[GPW];
#pragma unroll
    for (int g = 0; g < GPW; ++g) {
        const long long grp = g0 + g;
        xv[g] = (grp < ngroups) ? x[grp * 64 + lane] : 0.f;
    }

#pragma unroll
    for (int g = 0; g < GPW; ++g) {
        const long long grp = g0 + g;
        if (grp >= ngroups) break;
        const float v = xv[g];
#pragma unroll
        for (int m = 0; m < 4; ++m) {                     // row within group
            float* orow = out + (grp * 4 + m) * OUTD;
#pragma unroll
            for (int k = 0; k < 3; ++k) {
                const int c = k * 64 + lane;
                const float a  = __shfl(v, m * 16 + ii[k], 64);
                const float b  = __shfl(v, m * 16 + jj[k], 64);
                const float be = quad[k] ? b : 1.0f;
                float val = a * be * sc[k];
                if (k == 0 && c == 0) val = 1.0f;         // the leading ones column
                if (c < OUTD) orow[c] = val;              // 256B coalesced dword store
            }
        }
    }
}

extern "C" void kernel_launch(void* const* d_in, const int* in_sizes, int n_in,
                              void* d_out, int out_size, void* d_ws, size_t ws_size,
                              hipStream_t stream) {
    const float* x = (const float*)d_in[0];
    float* out = (float*)d_out;
    const int nrows = in_sizes[0] / D;                    // 4*16*8192 = 524288
    const int ngroups = nrows >> 2;                       // 131072
    const int waves_needed = (ngroups + GPW - 1) / GPW;   // 65536
    const int blocks = (waves_needed + 3) / 4;            // 16384
    taylor_fm_kernel<<<blocks, THREADS, 0, stream>>>(x, out, nrows);
}